// Round 13
// baseline (292.988 us; speedup 1.0000x reference)
//
#include <hip/hip_runtime.h>

#define NN 50000
#define NP 50048   // NN padded to 64 rows for MFMA tiles
#define NE 800000
#define DM 128
#define NH 8
#define DE 32
#define DG 64
#define MAXDEG 64
#define LOG2E 1.44269504088896f
#define SHIFT 16.0f

typedef __attribute__((ext_vector_type(8))) short bf16x8;
typedef __attribute__((ext_vector_type(4))) float f32x4;

__device__ __forceinline__ unsigned short f2bf(float f) {
    unsigned u = __float_as_uint(f);
    unsigned r = u + 0x7FFFu + ((u >> 16) & 1u);
    return (unsigned short)(r >> 16);
}

// sum over each 16-lane row via 4 full-rate DPP adds (no LDS pipe).
__device__ __forceinline__ float red16(float x) {
    float v = x;
    int t;
    t = __builtin_amdgcn_update_dpp(0, __float_as_int(v), 0xB1, 0xF, 0xF, true);  // quad_perm xor1
    v += __int_as_float(t);
    t = __builtin_amdgcn_update_dpp(0, __float_as_int(v), 0x4E, 0xF, 0xF, true);  // quad_perm xor2
    v += __int_as_float(t);
    t = __builtin_amdgcn_update_dpp(0, __float_as_int(v), 0x141, 0xF, 0xF, true); // row_half_mirror
    v += __int_as_float(t);
    t = __builtin_amdgcn_update_dpp(0, __float_as_int(v), 0x140, 0xF, 0xF, true); // row_mirror
    v += __int_as_float(t);
    return v;
}

// prep: weight transposes (bf16) + fused M = QSC*(Wq@Wek^T-blockdiag) + cnt=0.
__global__ void k_prep(const float* __restrict__ Wq, const float* __restrict__ Wk,
                       const float* __restrict__ Wv, unsigned short* __restrict__ wt,
                       const float* __restrict__ Wo, unsigned short* __restrict__ wto,
                       const float* __restrict__ Wek, unsigned short* __restrict__ wekq_t,
                       const float* __restrict__ Wg1, unsigned short* __restrict__ wg1t,
                       const float* __restrict__ Wg2, unsigned short* __restrict__ wg2t,
                       int* __restrict__ cnt) {
    int idx = blockIdx.x * 256 + threadIdx.x;
    if (idx < 3 * DM * DM) {
        int m = idx >> 14, rem = idx & 16383, c = rem >> 7, kk = rem & 127;
        const float* W = m == 0 ? Wq : (m == 1 ? Wk : Wv);
        wt[idx] = f2bf(W[kk * DM + c]);
    }
    if (idx < DM * DM) {
        int c = idx >> 7, kk = idx & 127;
        wto[idx] = f2bf(Wo[kk * DM + c]);
    }
    if (idx < 256 * DM) {
        // M^T[c][d0], c = h*32+i: qwek[n,c] = sum_d0 x[n,d0]*M[d0,c]
        int c = idx >> 7, d0 = idx & 127;
        int h = c >> 5, i = c & 31;
        float acc = 0.f;
        #pragma unroll
        for (int d = 0; d < 16; ++d)
            acc += Wq[(size_t)d0 * DM + h * 16 + d] * Wek[(size_t)i * DM + h * 16 + d];
        wekq_t[(size_t)c * DM + d0] = f2bf(acc * (0.25f * LOG2E));
    }
    if (idx < DG * DE) {
        int c = idx >> 5, kk = idx & 31;
        wg1t[idx] = f2bf(Wg1[kk * DG + c]);
    }
    if (idx < 16 * DG) {
        int c = idx >> 6, kk = idx & 63;
        wg2t[idx] = (c < NH) ? f2bf(Wg2[kk * NH + c]) : (unsigned short)0;
    }
    if (idx < NN) cnt[idx] = 0;
}

// q,k,v = x @ {Wq,Wk,Wv} via bf16 MFMA; x converted inline; q pre-scaled by QSC.
// Also qwek = x @ M (two extra MFMA phases), stored as bf16 (packed-pair layout).
__global__ __launch_bounds__(256) void k_qkv(
    const float* __restrict__ x, const unsigned short* __restrict__ wt,
    const unsigned short* __restrict__ wekq_t,
    float* __restrict__ q, unsigned* __restrict__ kvp,
    unsigned short* __restrict__ qwekh16) {
    int lane = threadIdx.x & 63;
    int w = threadIdx.x >> 6;
    int rt = blockIdx.x * 64 + w * 16;
    int cl = lane & 15;
    int kc = (lane >> 4) * 8;
    bool valid = (rt + cl) < NN;
    bf16x8 a[4];
    #pragma unroll
    for (int ks = 0; ks < 4; ++ks) {
        float4 f0 = make_float4(0.f, 0.f, 0.f, 0.f), f1 = f0;
        if (valid) {
            const float* xp = x + (size_t)(rt + cl) * DM + ks * 32 + kc;
            f0 = *(const float4*)xp;
            f1 = *(const float4*)(xp + 4);
        }
        bf16x8 av;
        av[0] = (short)f2bf(f0.x); av[1] = (short)f2bf(f0.y);
        av[2] = (short)f2bf(f0.z); av[3] = (short)f2bf(f0.w);
        av[4] = (short)f2bf(f1.x); av[5] = (short)f2bf(f1.y);
        av[6] = (short)f2bf(f1.z); av[7] = (short)f2bf(f1.w);
        a[ks] = av;
    }
    int r0w = rt + (lane >> 4) * 4;
    const float QSC = 0.25f * LOG2E;
    #pragma unroll
    for (int m = 0; m < 3; ++m) {
        const unsigned short* wtm = wt + m * DM * DM;
        f32x4 acc[8];
        #pragma unroll
        for (int j = 0; j < 8; ++j) acc[j] = (f32x4){0.f, 0.f, 0.f, 0.f};
        #pragma unroll
        for (int j = 0; j < 8; ++j) {
            #pragma unroll
            for (int ks = 0; ks < 4; ++ks) {
                bf16x8 b = *(const bf16x8*)(wtm + (size_t)(j * 16 + cl) * DM + ks * 32 + kc);
                acc[j] = __builtin_amdgcn_mfma_f32_16x16x32_bf16(a[ks], b, acc[j], 0, 0, 0);
            }
        }
        if (m == 0) {
            #pragma unroll
            for (int j = 0; j < 8; ++j)
                #pragma unroll
                for (int r = 0; r < 4; ++r)
                    q[(size_t)(r0w + r) * DM + j * 16 + cl] = acc[j][r] * QSC;
        } else {
            #pragma unroll
            for (int j = 0; j < 4; ++j)
                #pragma unroll
                for (int r = 0; r < 4; ++r) {
                    unsigned pk = (unsigned)f2bf(acc[j][r]) | ((unsigned)f2bf(acc[j + 4][r]) << 16);
                    kvp[(size_t)(r0w + r) * DM + 2 * (j * 16 + cl) + (m - 1)] = pk;
                }
        }
    }
    // qwek phases: cols [0,128) and [128,256) of x @ M
    #pragma unroll
    for (int m = 0; m < 2; ++m) {
        const unsigned short* wtm = wekq_t + (size_t)m * 128 * DM;
        f32x4 acc[8];
        #pragma unroll
        for (int j = 0; j < 8; ++j) acc[j] = (f32x4){0.f, 0.f, 0.f, 0.f};
        #pragma unroll
        for (int j = 0; j < 8; ++j) {
            #pragma unroll
            for (int ks = 0; ks < 4; ++ks) {
                bf16x8 b = *(const bf16x8*)(wtm + (size_t)(j * 16 + cl) * DM + ks * 32 + kc);
                acc[j] = __builtin_amdgcn_mfma_f32_16x16x32_bf16(a[ks], b, acc[j], 0, 0, 0);
            }
        }
        #pragma unroll
        for (int j = 0; j < 8; ++j)
            #pragma unroll
            for (int r = 0; r < 4; ++r)
                qwekh16[(size_t)(r0w + r) * 256 + m * 128 + j * 16 + cl] = f2bf(acc[j][r]);
    }
}

// per-edge (wave = 16 edges, MFMA gate MLP): g2 = gate*log2e - SHIFT,
// eah = ea in packed bf16 pairs, bucket (e,src) by dst.
__global__ __launch_bounds__(256) void k_edge(
    const float* __restrict__ ea,
    const unsigned short* __restrict__ wg1t, const unsigned short* __restrict__ wg2t,
    const int* __restrict__ ei, int* __restrict__ cnt,
    int2* __restrict__ eb, float2* __restrict__ g2, unsigned* __restrict__ eah) {
    __shared__ unsigned short hls[4][16 * 64];
    int lane = threadIdx.x & 63;
    int wv = threadIdx.x >> 6;
    int e0 = (blockIdx.x * 4 + wv) * 16;
    int cl = lane & 15;
    int g = lane >> 4;
    int kc = g * 8;

    const float* ear = ea + (size_t)(e0 + cl) * DE + kc;
    float4 f0 = *(const float4*)ear;
    float4 f1 = *(const float4*)(ear + 4);
    bf16x8 a;
    a[0] = (short)f2bf(f0.x); a[1] = (short)f2bf(f0.y);
    a[2] = (short)f2bf(f0.z); a[3] = (short)f2bf(f0.w);
    a[4] = (short)f2bf(f1.x); a[5] = (short)f2bf(f1.y);
    a[6] = (short)f2bf(f1.z); a[7] = (short)f2bf(f1.w);
    *(bf16x8*)(eah + (size_t)(e0 + cl) * 16 + kc / 2) = a;

    // stage 1: H[16 edges][64 hidden] = ea @ Wg1
    f32x4 hC[4];
    #pragma unroll
    for (int j = 0; j < 4; ++j) {
        bf16x8 b = *(const bf16x8*)(wg1t + (size_t)(j * 16 + cl) * DE + kc);
        hC[j] = __builtin_amdgcn_mfma_f32_16x16x32_bf16(a, b, (f32x4){0.f, 0.f, 0.f, 0.f}, 0, 0, 0);
    }

    // silu -> bf16 -> LDS (transposed layout, XOR-swizzled rows)
    unsigned short* hw = hls[wv];
    #pragma unroll
    for (int j = 0; j < 4; ++j) {
        #pragma unroll
        for (int r = 0; r < 4; ++r) {
            float h = hC[j][r];
            float s = h * __frcp_rn(1.f + __builtin_amdgcn_exp2f(-LOG2E * h));
            int rowE = g * 4 + r;
            int byte = ((rowE * 128) + (j * 16 + cl) * 2) ^ ((rowE & 7) << 4);
            *(unsigned short*)((char*)hw + byte) = f2bf(s);
        }
    }
    __syncthreads();

    // stage 2: out[16 edges][heads] = Hs @ Wg2  (k=64 -> two mfma)
    int rb0 = ((cl * 128) + g * 16) ^ ((cl & 7) << 4);
    int rb1 = ((cl * 128) + 64 + g * 16) ^ ((cl & 7) << 4);
    bf16x8 a2lo = *(bf16x8*)((char*)hw + rb0);
    bf16x8 a2hi = *(bf16x8*)((char*)hw + rb1);
    bf16x8 b2lo = *(const bf16x8*)(wg2t + (size_t)cl * DG + kc);
    bf16x8 b2hi = *(const bf16x8*)(wg2t + (size_t)cl * DG + 32 + kc);
    f32x4 c2 = __builtin_amdgcn_mfma_f32_16x16x32_bf16(a2lo, b2lo, (f32x4){0.f, 0.f, 0.f, 0.f}, 0, 0, 0);
    c2 = __builtin_amdgcn_mfma_f32_16x16x32_bf16(a2hi, b2hi, c2, 0, 0, 0);

    // scale, pair (h, h+4) via shfl_xor(4), store g2
    #pragma unroll
    for (int r = 0; r < 4; ++r) {
        float val = c2[r] * LOG2E - SHIFT;
        float other = __shfl_xor(val, 4);
        if (cl < 4)
            g2[(size_t)(e0 + g * 4 + r) * 4 + cl] = make_float2(val, other);
    }

    // bucket fill (lanes 0..15 handle this wave's 16 edges)
    if (lane < 16) {
        int e = e0 + lane;
        int src = ei[e], dst = ei[NE + e];
        int slot = atomicAdd(&cnt[dst], 1);
        if (slot < MAXDEG) eb[(size_t)dst * MAXDEG + slot] = make_int2(e, src);
    }
}

// no-max softmax body: px = exp2(score + g_shifted); pure accumulate.
#define ECOMP(KV, EAU, G, QA, QB, QWA, QWB, LA, LB, AA, AB, E0, E1, E2, E3) {     \
    unsigned kw = (unsigned)(KV), vw = (unsigned)((KV) >> 32);                    \
    float kA = __uint_as_float(kw << 16);                                         \
    float kB = __uint_as_float(kw & 0xFFFF0000u);                                 \
    float vA = __uint_as_float(vw << 16);                                         \
    float vB = __uint_as_float(vw & 0xFFFF0000u);                                 \
    float eax = __uint_as_float((EAU) << 16);                                     \
    float eay = __uint_as_float((EAU) & 0xFFFF0000u);                             \
    float pA = QA * kA + eax * QWA.x + eay * QWA.y;                               \
    float pB = QB * kB + eax * QWB.x + eay * QWB.y;                               \
    pA = red16(pA);                                                               \
    pB = red16(pB);                                                               \
    float pxA = __builtin_amdgcn_exp2f(pA + G.x);                                 \
    float pxB = __builtin_amdgcn_exp2f(pB + G.y);                                 \
    LA += pxA;  LB += pxB;                                                        \
    AA += pxA * vA;  AB += pxB * vB;                                              \
    E0 += pxA * eax;  E1 += pxA * eay;                                            \
    E2 += pxB * eax;  E3 += pxB * eay;                                            \
}

#define LOADGEN(JIDX, EVV, SVV, KDST, EDST, GDST) {                               \
    int e_ = __builtin_amdgcn_readlane(EVV, JIDX);                                \
    int s_ = __builtin_amdgcn_readlane(SVV, JIDX);                                \
    KDST = kvp[(size_t)s_ * 64 + lane];                                           \
    EDST = eah[(size_t)e_ * 16 + i2];                                             \
    GDST = *(const float2*)(g2f + (size_t)e_ * 8 + hA * 2);                       \
}

// 2-wave blocks (128 thr): 16 wg/CU limit * 2 waves -> full occupancy headroom.
// wave = 2 dst nodes; u64 kv gather; DEPTH-3 ping-pong prefetch; DPP reduce.
__global__ __launch_bounds__(128) void k_fused(
    const float* __restrict__ q, const unsigned long long* __restrict__ kvp,
    const unsigned* __restrict__ qwekh, const float* __restrict__ g2f,
    const unsigned* __restrict__ eah, const int2* __restrict__ eb,
    const int* __restrict__ cnt, const float* __restrict__ Wev,
    float* __restrict__ outb) {
    int lane = threadIdx.x & 63;
    int gwid = blockIdx.x * 2 + (threadIdx.x >> 6);
    int n0 = gwid * 2, n1 = n0 + 1;
    int hA = lane >> 4;
    int i2 = lane & 15;

    int deg0 = cnt[n0]; deg0 = deg0 > MAXDEG ? MAXDEG : deg0;
    int deg1 = cnt[n1]; deg1 = deg1 > MAXDEG ? MAXDEG : deg1;
    int s0 = lane < deg0 ? lane : 0;
    int s1 = lane < deg1 ? lane : 0;
    int2 t0 = eb[(size_t)n0 * MAXDEG + s0];
    int2 t1 = eb[(size_t)n1 * MAXDEG + s1];
    if (deg0 == 0) { t0.x = 0; t0.y = 0; }
    if (deg1 == 0) { t1.x = 0; t1.y = 0; }
    int ev0 = t0.x, sv0 = t0.y, ev1 = t1.x, sv1 = t1.y;

    float qA0 = q[(size_t)n0 * DM + lane], qB0 = q[(size_t)n0 * DM + 64 + lane];
    float qA1 = q[(size_t)n1 * DM + lane], qB1 = q[(size_t)n1 * DM + 64 + lane];
    unsigned uA0 = qwekh[(size_t)n0 * 128 + hA * 16 + i2];
    unsigned uB0 = qwekh[(size_t)n0 * 128 + (hA + 4) * 16 + i2];
    unsigned uA1 = qwekh[(size_t)n1 * 128 + hA * 16 + i2];
    unsigned uB1 = qwekh[(size_t)n1 * 128 + (hA + 4) * 16 + i2];
    float2 qwA0 = make_float2(__uint_as_float(uA0 << 16), __uint_as_float(uA0 & 0xFFFF0000u));
    float2 qwB0 = make_float2(__uint_as_float(uB0 << 16), __uint_as_float(uB0 & 0xFFFF0000u));
    float2 qwA1 = make_float2(__uint_as_float(uA1 << 16), __uint_as_float(uA1 & 0xFFFF0000u));
    float2 qwB1 = make_float2(__uint_as_float(uB1 << 16), __uint_as_float(uB1 & 0xFFFF0000u));

    float lA0 = 0.f, lB0 = 0.f, aA0 = 0.f, aB0 = 0.f;
    float e00 = 0.f, e01 = 0.f, e02 = 0.f, e03 = 0.f;
    float lA1 = 0.f, lB1 = 0.f, aA1 = 0.f, aB1 = 0.f;
    float e10 = 0.f, e11 = 0.f, e12 = 0.f, e13 = 0.f;

    int degm = deg0 > deg1 ? deg0 : deg1;

    // depth-3 ping-pong generations A (j), B (j+1), C (j+2)
    unsigned long long kvA0, kvA1, kvB0, kvB1, kvC0, kvC1;
    unsigned eaA0, eaA1, eaB0, eaB1, eaC0, eaC1;
    float2 gA0, gA1, gB0, gB1, gC0, gC1;
    LOADGEN(0, ev0, sv0, kvA0, eaA0, gA0)
    LOADGEN(0, ev1, sv1, kvA1, eaA1, gA1)
    LOADGEN(1, ev0, sv0, kvB0, eaB0, gB0)
    LOADGEN(1, ev1, sv1, kvB1, eaB1, gB1)
    LOADGEN(2, ev0, sv0, kvC0, eaC0, gC0)
    LOADGEN(2, ev1, sv1, kvC1, eaC1, gC1)

    int jmax = degm - 1;
    for (int j = 0; j < degm; j += 3) {
        if (j < deg0) ECOMP(kvA0, eaA0, gA0, qA0, qB0, qwA0, qwB0, lA0, lB0, aA0, aB0, e00, e01, e02, e03)
        int jp = j + 3 < jmax ? j + 3 : jmax;
        LOADGEN(jp, ev0, sv0, kvA0, eaA0, gA0)
        if (j < deg1) ECOMP(kvA1, eaA1, gA1, qA1, qB1, qwA1, qwB1, lA1, lB1, aA1, aB1, e10, e11, e12, e13)
        LOADGEN(jp, ev1, sv1, kvA1, eaA1, gA1)
        if (j + 1 < deg0) ECOMP(kvB0, eaB0, gB0, qA0, qB0, qwA0, qwB0, lA0, lB0, aA0, aB0, e00, e01, e02, e03)
        int jq = j + 4 < jmax ? j + 4 : jmax;
        LOADGEN(jq, ev0, sv0, kvB0, eaB0, gB0)
        if (j + 1 < deg1) ECOMP(kvB1, eaB1, gB1, qA1, qB1, qwA1, qwB1, lA1, lB1, aA1, aB1, e10, e11, e12, e13)
        LOADGEN(jq, ev1, sv1, kvB1, eaB1, gB1)
        if (j + 2 < deg0) ECOMP(kvC0, eaC0, gC0, qA0, qB0, qwA0, qwB0, lA0, lB0, aA0, aB0, e00, e01, e02, e03)
        int jr = j + 5 < jmax ? j + 5 : jmax;
        LOADGEN(jr, ev0, sv0, kvC0, eaC0, gC0)
        if (j + 2 < deg1) ECOMP(kvC1, eaC1, gC1, qA1, qB1, qwA1, qwB1, lA1, lB1, aA1, aB1, e10, e11, e12, e13)
        LOADGEN(jr, ev1, sv1, kvC1, eaC1, gC1)
    }

    // epilogue: enrichment = eagg @ Wev (Wev from global, shared by both nodes)
    int basel = lane & 48;
    float enA0 = 0.f, enB0 = 0.f, enA1 = 0.f, enB1 = 0.f;
    #pragma unroll
    for (int i = 0; i < DE; i += 2) {
        int sl = basel | (i >> 1);
        float w0A = Wev[i * DM + lane],      w1A = Wev[(i + 1) * DM + lane];
        float w0B = Wev[i * DM + 64 + lane], w1B = Wev[(i + 1) * DM + 64 + lane];
        enA0 += __shfl(e00, sl) * w0A + __shfl(e01, sl) * w1A;
        enB0 += __shfl(e02, sl) * w0B + __shfl(e03, sl) * w1B;
        enA1 += __shfl(e10, sl) * w0A + __shfl(e11, sl) * w1A;
        enB1 += __shfl(e12, sl) * w0B + __shfl(e13, sl) * w1B;
    }
    outb[(size_t)n0 * DM + lane]      = (aA0 + enA0) / fmaxf(lA0, 1e-30f);
    outb[(size_t)n0 * DM + 64 + lane] = (aB0 + enB0) / fmaxf(lB0, 1e-30f);
    outb[(size_t)n1 * DM + lane]      = (aA1 + enA1) / fmaxf(lA1, 1e-30f);
    outb[(size_t)n1 * DM + 64 + lane] = (aB1 + enB1) / fmaxf(lB1, 1e-30f);
}

// d_out = d_out @ Wo in place via bf16 MFMA.  Wave = 16 rows (owned exclusively).
__global__ __launch_bounds__(256) void k_final(
    float* __restrict__ dout, const unsigned short* __restrict__ wto) {
    int lane = threadIdx.x & 63;
    int w = threadIdx.x >> 6;
    int rt = blockIdx.x * 64 + w * 16;
    if (rt >= NN) return;
    int cl = lane & 15;
    int kc = (lane >> 4) * 8;
    bf16x8 a[4];
    #pragma unroll
    for (int ks = 0; ks < 4; ++ks) {
        float4 f0 = *(const float4*)(dout + (size_t)(rt + cl) * DM + ks * 32 + kc);
        float4 f1 = *(const float4*)(dout + (size_t)(rt + cl) * DM + ks * 32 + kc + 4);
        bf16x8 av;
        av[0] = (short)f2bf(f0.x); av[1] = (short)f2bf(f0.y);
        av[2] = (short)f2bf(f0.z); av[3] = (short)f2bf(f0.w);
        av[4] = (short)f2bf(f1.x); av[5] = (short)f2bf(f1.y);
        av[6] = (short)f2bf(f1.z); av[7] = (short)f2bf(f1.w);
        a[ks] = av;
    }
    f32x4 acc[8];
    #pragma unroll
    for (int j = 0; j < 8; ++j) acc[j] = (f32x4){0.f, 0.f, 0.f, 0.f};
    #pragma unroll
    for (int j = 0; j < 8; ++j) {
        #pragma unroll
        for (int ks = 0; ks < 4; ++ks) {
            bf16x8 b = *(const bf16x8*)(wto + (size_t)(j * 16 + cl) * DM + ks * 32 + kc);
            acc[j] = __builtin_amdgcn_mfma_f32_16x16x32_bf16(a[ks], b, acc[j], 0, 0, 0);
        }
    }
    int r0w = rt + (lane >> 4) * 4;
    #pragma unroll
    for (int j = 0; j < 8; ++j)
        #pragma unroll
        for (int r = 0; r < 4; ++r)
            dout[(size_t)(r0w + r) * DM + j * 16 + cl] = acc[j][r];
}

extern "C" void kernel_launch(void* const* d_in, const int* in_sizes, int n_in,
                              void* d_out, int out_size, void* d_ws, size_t ws_size,
                              hipStream_t stream) {
    const float* x   = (const float*)d_in[0];
    const int*   ei  = (const int*)d_in[1];
    const float* ea  = (const float*)d_in[2];
    const float* Wq  = (const float*)d_in[3];
    const float* Wk  = (const float*)d_in[4];
    const float* Wv  = (const float*)d_in[5];
    const float* Wo  = (const float*)d_in[6];
    const float* Wek = (const float*)d_in[7];
    const float* Wev = (const float*)d_in[8];
    const float* Wg1 = (const float*)d_in[9];
    const float* Wg2 = (const float*)d_in[10];
    float* dout = (float*)d_out;

    float* ws = (float*)d_ws;
    float* q        = ws;                                   // NP*DM f32
    unsigned* kvp   = (unsigned*)(q + (size_t)NP * DM);     // NP*DM u32
    unsigned* qwekh = kvp + (size_t)NP * DM;                // NP*128 u32 (bf16 pairs)
    float* g2f      = (float*)(qwekh + (size_t)NP * 128);   // NE*8 f32
    int2* eb        = (int2*)(g2f + (size_t)NE * 8);        // NN*MAXDEG int2
    unsigned* eah   = (unsigned*)(eb + (size_t)NN * MAXDEG);// NE*16 u32 (bf16 pairs)
    int* cnt        = (int*)(eah + (size_t)NE * 16);        // NN
    unsigned short* wt = (unsigned short*)(cnt + NN);       // 3*DM*DM bf16
    unsigned short* wto = wt + 3 * DM * DM;                 // DM*DM bf16
    unsigned short* wg1t = wto + DM * DM;                   // DG*DE bf16
    unsigned short* wg2t = wg1t + DG * DE;                  // 16*DG bf16
    unsigned short* wekq_t = wg2t + 16 * DG;                // 256*DM bf16

    k_prep<<<(NN + 255) / 256, 256, 0, stream>>>(Wq, Wk, Wv, wt, Wo, wto, Wek, wekq_t,
                                                 Wg1, wg1t, Wg2, wg2t, cnt);
    k_qkv<<<NP / 64, 256, 0, stream>>>(x, wt, wekq_t, q, kvp, (unsigned short*)qwekh);
    k_edge<<<NE / 64, 256, 0, stream>>>(ea, wg1t, wg2t, ei, cnt, eb, (float2*)g2f, eah);
    k_fused<<<NN / 4, 128, 0, stream>>>(q, (const unsigned long long*)kvp,
                                        qwekh, g2f, eah, eb, cnt, Wev, dout);
    k_final<<<(NN + 63) / 64, 256, 0, stream>>>(dout, wto);
}

// Round 14
// 282.214 us; speedup vs baseline: 1.0382x; 1.0382x over previous
//
#include <hip/hip_runtime.h>

#define NN 50000
#define NP 50048   // NN padded to 64 rows for MFMA tiles
#define NE 800000
#define DM 128
#define NH 8
#define DE 32
#define DG 64
#define MAXDEG 64
#define LOG2E 1.44269504088896f
#define SHIFT 16.0f

typedef __attribute__((ext_vector_type(8))) short bf16x8;
typedef __attribute__((ext_vector_type(4))) float f32x4;
typedef __attribute__((ext_vector_type(2))) float f32x2;

__device__ __forceinline__ unsigned short f2bf(float f) {
    unsigned u = __float_as_uint(f);
    unsigned r = u + 0x7FFFu + ((u >> 16) & 1u);
    return (unsigned short)(r >> 16);
}

// prep: weight transposes (bf16) + WekT + cnt=0.
__global__ void k_prep(const float* __restrict__ Wq, const float* __restrict__ Wk,
                       const float* __restrict__ Wv, unsigned short* __restrict__ wt,
                       const float* __restrict__ Wo, unsigned short* __restrict__ wto,
                       const float* __restrict__ Wek, float* __restrict__ WekT,
                       const float* __restrict__ Wg1, unsigned short* __restrict__ wg1t,
                       const float* __restrict__ Wg2, unsigned short* __restrict__ wg2t,
                       int* __restrict__ cnt) {
    int idx = blockIdx.x * 256 + threadIdx.x;
    if (idx < 3 * DM * DM) {
        int m = idx >> 14, rem = idx & 16383, c = rem >> 7, kk = rem & 127;
        const float* W = m == 0 ? Wq : (m == 1 ? Wk : Wv);
        wt[idx] = f2bf(W[kk * DM + c]);
    }
    if (idx < DM * DM) {
        int c = idx >> 7, kk = idx & 127;
        wto[idx] = f2bf(Wo[kk * DM + c]);
    }
    if (idx < DE * DM) {
        int d = idx >> 5, i = idx & 31;
        WekT[idx] = Wek[i * DM + d];
    }
    if (idx < DG * DE) {
        int c = idx >> 5, kk = idx & 31;
        wg1t[idx] = f2bf(Wg1[kk * DG + c]);
    }
    if (idx < 16 * DG) {
        int c = idx >> 6, kk = idx & 63;
        wg2t[idx] = (c < NH) ? f2bf(Wg2[kk * NH + c]) : (unsigned short)0;
    }
    if (idx < NN) cnt[idx] = 0;
}

// q,k,v = x @ {Wq,Wk,Wv} via bf16 MFMA; x converted inline; q pre-scaled by QSC.
__global__ __launch_bounds__(256) void k_qkv(
    const float* __restrict__ x, const unsigned short* __restrict__ wt,
    float* __restrict__ q, unsigned* __restrict__ kvp) {
    int lane = threadIdx.x & 63;
    int w = threadIdx.x >> 6;
    int rt = blockIdx.x * 64 + w * 16;
    int cl = lane & 15;
    int kc = (lane >> 4) * 8;
    bool valid = (rt + cl) < NN;
    bf16x8 a[4];
    #pragma unroll
    for (int ks = 0; ks < 4; ++ks) {
        float4 f0 = make_float4(0.f, 0.f, 0.f, 0.f), f1 = f0;
        if (valid) {
            const float* xp = x + (size_t)(rt + cl) * DM + ks * 32 + kc;
            f0 = *(const float4*)xp;
            f1 = *(const float4*)(xp + 4);
        }
        bf16x8 av;
        av[0] = (short)f2bf(f0.x); av[1] = (short)f2bf(f0.y);
        av[2] = (short)f2bf(f0.z); av[3] = (short)f2bf(f0.w);
        av[4] = (short)f2bf(f1.x); av[5] = (short)f2bf(f1.y);
        av[6] = (short)f2bf(f1.z); av[7] = (short)f2bf(f1.w);
        a[ks] = av;
    }
    int r0w = rt + (lane >> 4) * 4;
    const float QSC = 0.25f * LOG2E;
    #pragma unroll
    for (int m = 0; m < 3; ++m) {
        const unsigned short* wtm = wt + m * DM * DM;
        f32x4 acc[8];
        #pragma unroll
        for (int j = 0; j < 8; ++j) acc[j] = (f32x4){0.f, 0.f, 0.f, 0.f};
        #pragma unroll
        for (int j = 0; j < 8; ++j) {
            #pragma unroll
            for (int ks = 0; ks < 4; ++ks) {
                bf16x8 b = *(const bf16x8*)(wtm + (size_t)(j * 16 + cl) * DM + ks * 32 + kc);
                acc[j] = __builtin_amdgcn_mfma_f32_16x16x32_bf16(a[ks], b, acc[j], 0, 0, 0);
            }
        }
        if (m == 0) {
            #pragma unroll
            for (int j = 0; j < 8; ++j)
                #pragma unroll
                for (int r = 0; r < 4; ++r)
                    q[(size_t)(r0w + r) * DM + j * 16 + cl] = acc[j][r] * QSC;
        } else {
            #pragma unroll
            for (int j = 0; j < 4; ++j)
                #pragma unroll
                for (int r = 0; r < 4; ++r) {
                    unsigned pk = (unsigned)f2bf(acc[j][r]) | ((unsigned)f2bf(acc[j + 4][r]) << 16);
                    kvp[(size_t)(r0w + r) * DM + 2 * (j * 16 + cl) + (m - 1)] = pk;
                }
        }
    }
}

// qwekh = bf16 pairs of (q_scaled · WekT) — q already carries QSC.
__global__ __launch_bounds__(256) void k_qwek(
    const float* __restrict__ q, const float* __restrict__ WekT,
    unsigned* __restrict__ qwekh) {
    int t = threadIdx.x & 127;
    int sub = threadIdx.x >> 7;
    int h = t >> 4, i2 = t & 15;
    float wk0[16], wk1[16];
    #pragma unroll
    for (int d = 0; d < 16; ++d) {
        wk0[d] = WekT[(h * 16 + d) * 32 + 2 * i2];
        wk1[d] = WekT[(h * 16 + d) * 32 + 2 * i2 + 1];
    }
    for (int n = blockIdx.x * 2 + sub; n < NN; n += gridDim.x * 2) {
        const float4* qr = (const float4*)(q + (size_t)n * DM + h * 16);
        float a0 = 0.f, a1 = 0.f;
        #pragma unroll
        for (int c = 0; c < 4; ++c) {
            float4 qq = qr[c];
            a0 += qq.x * wk0[4*c] + qq.y * wk0[4*c+1] + qq.z * wk0[4*c+2] + qq.w * wk0[4*c+3];
            a1 += qq.x * wk1[4*c] + qq.y * wk1[4*c+1] + qq.z * wk1[4*c+2] + qq.w * wk1[4*c+3];
        }
        qwekh[(size_t)n * 128 + h * 16 + i2] = (unsigned)f2bf(a0) | ((unsigned)f2bf(a1) << 16);
    }
}

// per-edge (wave = 16 edges, MFMA gate MLP): g2 = gate*log2e - SHIFT,
// eah = ea in packed bf16 pairs, bucket (e,src) by dst.
__global__ __launch_bounds__(256) void k_edge(
    const float* __restrict__ ea,
    const unsigned short* __restrict__ wg1t, const unsigned short* __restrict__ wg2t,
    const int* __restrict__ ei, int* __restrict__ cnt,
    int2* __restrict__ eb, float2* __restrict__ g2, unsigned* __restrict__ eah) {
    __shared__ unsigned short hls[4][16 * 64];
    int lane = threadIdx.x & 63;
    int wv = threadIdx.x >> 6;
    int e0 = (blockIdx.x * 4 + wv) * 16;
    int cl = lane & 15;
    int g = lane >> 4;
    int kc = g * 8;

    const float* ear = ea + (size_t)(e0 + cl) * DE + kc;
    float4 f0 = *(const float4*)ear;
    float4 f1 = *(const float4*)(ear + 4);
    bf16x8 a;
    a[0] = (short)f2bf(f0.x); a[1] = (short)f2bf(f0.y);
    a[2] = (short)f2bf(f0.z); a[3] = (short)f2bf(f0.w);
    a[4] = (short)f2bf(f1.x); a[5] = (short)f2bf(f1.y);
    a[6] = (short)f2bf(f1.z); a[7] = (short)f2bf(f1.w);
    *(bf16x8*)(eah + (size_t)(e0 + cl) * 16 + kc / 2) = a;

    // stage 1: H[16 edges][64 hidden] = ea @ Wg1
    f32x4 hC[4];
    #pragma unroll
    for (int j = 0; j < 4; ++j) {
        bf16x8 b = *(const bf16x8*)(wg1t + (size_t)(j * 16 + cl) * DE + kc);
        hC[j] = __builtin_amdgcn_mfma_f32_16x16x32_bf16(a, b, (f32x4){0.f, 0.f, 0.f, 0.f}, 0, 0, 0);
    }

    // silu -> bf16 -> LDS (transposed layout, XOR-swizzled rows)
    unsigned short* hw = hls[wv];
    #pragma unroll
    for (int j = 0; j < 4; ++j) {
        #pragma unroll
        for (int r = 0; r < 4; ++r) {
            float h = hC[j][r];
            float s = h * __frcp_rn(1.f + __builtin_amdgcn_exp2f(-LOG2E * h));
            int rowE = g * 4 + r;
            int byte = ((rowE * 128) + (j * 16 + cl) * 2) ^ ((rowE & 7) << 4);
            *(unsigned short*)((char*)hw + byte) = f2bf(s);
        }
    }
    __syncthreads();

    // stage 2: out[16 edges][heads] = Hs @ Wg2  (k=64 -> two mfma)
    int rb0 = ((cl * 128) + g * 16) ^ ((cl & 7) << 4);
    int rb1 = ((cl * 128) + 64 + g * 16) ^ ((cl & 7) << 4);
    bf16x8 a2lo = *(bf16x8*)((char*)hw + rb0);
    bf16x8 a2hi = *(bf16x8*)((char*)hw + rb1);
    bf16x8 b2lo = *(const bf16x8*)(wg2t + (size_t)cl * DG + kc);
    bf16x8 b2hi = *(const bf16x8*)(wg2t + (size_t)cl * DG + 32 + kc);
    f32x4 c2 = __builtin_amdgcn_mfma_f32_16x16x32_bf16(a2lo, b2lo, (f32x4){0.f, 0.f, 0.f, 0.f}, 0, 0, 0);
    c2 = __builtin_amdgcn_mfma_f32_16x16x32_bf16(a2hi, b2hi, c2, 0, 0, 0);

    // scale, pair (h, h+4) via shfl_xor(4), store g2
    #pragma unroll
    for (int r = 0; r < 4; ++r) {
        float val = c2[r] * LOG2E - SHIFT;
        float other = __shfl_xor(val, 4);
        if (cl < 4)
            g2[(size_t)(e0 + g * 4 + r) * 4 + cl] = make_float2(val, other);
    }

    // bucket fill (lanes 0..15 handle this wave's 16 edges)
    if (lane < 16) {
        int e = e0 + lane;
        int src = ei[e], dst = ei[NE + e];
        int slot = atomicAdd(&cnt[dst], 1);
        if (slot < MAXDEG) eb[(size_t)dst * MAXDEG + slot] = make_int2(e, src);
    }
}

// no-max softmax body, PACKED f32x2 (A,B halves) -> v_pk_fma_f32 codegen.
#define ECOMP(KV, EAU, GAB, QAB, QWX, QWY, LAB, AAB, EX, EY) {                    \
    unsigned kw = (unsigned)(KV), vw = (unsigned)((KV) >> 32);                    \
    f32x2 kAB = {__uint_as_float(kw << 16), __uint_as_float(kw & 0xFFFF0000u)};   \
    f32x2 vAB = {__uint_as_float(vw << 16), __uint_as_float(vw & 0xFFFF0000u)};   \
    float eax = __uint_as_float((EAU) << 16);                                     \
    float eay = __uint_as_float((EAU) & 0xFFFF0000u);                             \
    f32x2 p = QAB * kAB;                                                          \
    p += (f32x2){eax, eax} * QWX;                                                 \
    p += (f32x2){eay, eay} * QWY;                                                 \
    int t0, t1;                                                                   \
    t0 = __builtin_amdgcn_update_dpp(0, __float_as_int(p.x), 0xB1, 0xF, 0xF, true); \
    t1 = __builtin_amdgcn_update_dpp(0, __float_as_int(p.y), 0xB1, 0xF, 0xF, true); \
    p += (f32x2){__int_as_float(t0), __int_as_float(t1)};                         \
    t0 = __builtin_amdgcn_update_dpp(0, __float_as_int(p.x), 0x4E, 0xF, 0xF, true); \
    t1 = __builtin_amdgcn_update_dpp(0, __float_as_int(p.y), 0x4E, 0xF, 0xF, true); \
    p += (f32x2){__int_as_float(t0), __int_as_float(t1)};                         \
    t0 = __builtin_amdgcn_update_dpp(0, __float_as_int(p.x), 0x141, 0xF, 0xF, true); \
    t1 = __builtin_amdgcn_update_dpp(0, __float_as_int(p.y), 0x141, 0xF, 0xF, true); \
    p += (f32x2){__int_as_float(t0), __int_as_float(t1)};                         \
    t0 = __builtin_amdgcn_update_dpp(0, __float_as_int(p.x), 0x140, 0xF, 0xF, true); \
    t1 = __builtin_amdgcn_update_dpp(0, __float_as_int(p.y), 0x140, 0xF, 0xF, true); \
    p += (f32x2){__int_as_float(t0), __int_as_float(t1)};                         \
    p += GAB;                                                                     \
    f32x2 px = {__builtin_amdgcn_exp2f(p.x), __builtin_amdgcn_exp2f(p.y)};        \
    LAB += px;                                                                    \
    AAB += px * vAB;                                                              \
    EX += (f32x2){px.x, px.x} * (f32x2){eax, eay};                                \
    EY += (f32x2){px.y, px.y} * (f32x2){eax, eay};                                \
}

#define LOADGEN(JIDX, EVV, SVV, KDST, EDST, GDST) {                               \
    int e_ = __builtin_amdgcn_readlane(EVV, JIDX);                                \
    int s_ = __builtin_amdgcn_readlane(SVV, JIDX);                                \
    KDST = kvp[(size_t)s_ * 64 + lane];                                           \
    EDST = eah[(size_t)e_ * 16 + i2];                                             \
    float2 gtmp_ = *(const float2*)(g2f + (size_t)e_ * 8 + hA * 2);               \
    GDST = (f32x2){gtmp_.x, gtmp_.y};                                             \
}

// wave = 2 dst nodes; u64 kv gather; depth-2 ping-pong prefetch; packed math.
__global__ __launch_bounds__(256) void k_fused(
    const float* __restrict__ q, const unsigned long long* __restrict__ kvp,
    const unsigned* __restrict__ qwekh, const float* __restrict__ g2f,
    const unsigned* __restrict__ eah, const int2* __restrict__ eb,
    const int* __restrict__ cnt, const float* __restrict__ Wev,
    float* __restrict__ outb) {
    int lane = threadIdx.x & 63;
    int gwid = blockIdx.x * 4 + (threadIdx.x >> 6);
    int n0 = gwid * 2, n1 = n0 + 1;
    int hA = lane >> 4;
    int i2 = lane & 15;

    int deg0 = cnt[n0]; deg0 = deg0 > MAXDEG ? MAXDEG : deg0;
    int deg1 = cnt[n1]; deg1 = deg1 > MAXDEG ? MAXDEG : deg1;
    int s0 = lane < deg0 ? lane : 0;
    int s1 = lane < deg1 ? lane : 0;
    int2 t0 = eb[(size_t)n0 * MAXDEG + s0];
    int2 t1 = eb[(size_t)n1 * MAXDEG + s1];
    if (deg0 == 0) { t0.x = 0; t0.y = 0; }
    if (deg1 == 0) { t1.x = 0; t1.y = 0; }
    int ev0 = t0.x, sv0 = t0.y, ev1 = t1.x, sv1 = t1.y;

    f32x2 QAB0 = {q[(size_t)n0 * DM + lane], q[(size_t)n0 * DM + 64 + lane]};
    f32x2 QAB1 = {q[(size_t)n1 * DM + lane], q[(size_t)n1 * DM + 64 + lane]};
    unsigned uA0 = qwekh[(size_t)n0 * 128 + hA * 16 + i2];
    unsigned uB0 = qwekh[(size_t)n0 * 128 + (hA + 4) * 16 + i2];
    unsigned uA1 = qwekh[(size_t)n1 * 128 + hA * 16 + i2];
    unsigned uB1 = qwekh[(size_t)n1 * 128 + (hA + 4) * 16 + i2];
    f32x2 QWX0 = {__uint_as_float(uA0 << 16), __uint_as_float(uB0 << 16)};
    f32x2 QWY0 = {__uint_as_float(uA0 & 0xFFFF0000u), __uint_as_float(uB0 & 0xFFFF0000u)};
    f32x2 QWX1 = {__uint_as_float(uA1 << 16), __uint_as_float(uB1 << 16)};
    f32x2 QWY1 = {__uint_as_float(uA1 & 0xFFFF0000u), __uint_as_float(uB1 & 0xFFFF0000u)};

    f32x2 LAB0 = {0.f, 0.f}, AAB0 = {0.f, 0.f}, EX0 = {0.f, 0.f}, EY0 = {0.f, 0.f};
    f32x2 LAB1 = {0.f, 0.f}, AAB1 = {0.f, 0.f}, EX1 = {0.f, 0.f}, EY1 = {0.f, 0.f};

    int degm = deg0 > deg1 ? deg0 : deg1;

    unsigned long long kvA0, kvA1, kvB0, kvB1;
    unsigned eaA0, eaA1, eaB0, eaB1;
    f32x2 gA0, gA1, gB0, gB1;
    LOADGEN(0, ev0, sv0, kvA0, eaA0, gA0)
    LOADGEN(0, ev1, sv1, kvA1, eaA1, gA1)
    LOADGEN(1, ev0, sv0, kvB0, eaB0, gB0)
    LOADGEN(1, ev1, sv1, kvB1, eaB1, gB1)

    int jmax = degm - 1;
    for (int j = 0; j < degm; j += 2) {
        if (j < deg0) ECOMP(kvA0, eaA0, gA0, QAB0, QWX0, QWY0, LAB0, AAB0, EX0, EY0)
        int jp = j + 2 < jmax ? j + 2 : jmax;
        LOADGEN(jp, ev0, sv0, kvA0, eaA0, gA0)
        if (j < deg1) ECOMP(kvA1, eaA1, gA1, QAB1, QWX1, QWY1, LAB1, AAB1, EX1, EY1)
        LOADGEN(jp, ev1, sv1, kvA1, eaA1, gA1)
        if (j + 1 < deg0) ECOMP(kvB0, eaB0, gB0, QAB0, QWX0, QWY0, LAB0, AAB0, EX0, EY0)
        int jq = j + 3 < jmax ? j + 3 : jmax;
        LOADGEN(jq, ev0, sv0, kvB0, eaB0, gB0)
        if (j + 1 < deg1) ECOMP(kvB1, eaB1, gB1, QAB1, QWX1, QWY1, LAB1, AAB1, EX1, EY1)
        LOADGEN(jq, ev1, sv1, kvB1, eaB1, gB1)
    }

    // epilogue: enrichment = eagg @ Wev (Wev from global, shared by both nodes)
    float e00 = EX0.x, e01 = EX0.y, e02 = EY0.x, e03 = EY0.y;
    float e10 = EX1.x, e11 = EX1.y, e12 = EY1.x, e13 = EY1.y;
    int basel = lane & 48;
    float enA0 = 0.f, enB0 = 0.f, enA1 = 0.f, enB1 = 0.f;
    #pragma unroll
    for (int i = 0; i < DE; i += 2) {
        int sl = basel | (i >> 1);
        float w0A = Wev[i * DM + lane],      w1A = Wev[(i + 1) * DM + lane];
        float w0B = Wev[i * DM + 64 + lane], w1B = Wev[(i + 1) * DM + 64 + lane];
        enA0 += __shfl(e00, sl) * w0A + __shfl(e01, sl) * w1A;
        enB0 += __shfl(e02, sl) * w0B + __shfl(e03, sl) * w1B;
        enA1 += __shfl(e10, sl) * w0A + __shfl(e11, sl) * w1A;
        enB1 += __shfl(e12, sl) * w0B + __shfl(e13, sl) * w1B;
    }
    outb[(size_t)n0 * DM + lane]      = (AAB0.x + enA0) / fmaxf(LAB0.x, 1e-30f);
    outb[(size_t)n0 * DM + 64 + lane] = (AAB0.y + enB0) / fmaxf(LAB0.y, 1e-30f);
    outb[(size_t)n1 * DM + lane]      = (AAB1.x + enA1) / fmaxf(LAB1.x, 1e-30f);
    outb[(size_t)n1 * DM + 64 + lane] = (AAB1.y + enB1) / fmaxf(LAB1.y, 1e-30f);
}

// d_out = d_out @ Wo in place via bf16 MFMA.  Wave = 16 rows (owned exclusively).
__global__ __launch_bounds__(256) void k_final(
    float* __restrict__ dout, const unsigned short* __restrict__ wto) {
    int lane = threadIdx.x & 63;
    int w = threadIdx.x >> 6;
    int rt = blockIdx.x * 64 + w * 16;
    if (rt >= NN) return;
    int cl = lane & 15;
    int kc = (lane >> 4) * 8;
    bf16x8 a[4];
    #pragma unroll
    for (int ks = 0; ks < 4; ++ks) {
        float4 f0 = *(const float4*)(dout + (size_t)(rt + cl) * DM + ks * 32 + kc);
        float4 f1 = *(const float4*)(dout + (size_t)(rt + cl) * DM + ks * 32 + kc + 4);
        bf16x8 av;
        av[0] = (short)f2bf(f0.x); av[1] = (short)f2bf(f0.y);
        av[2] = (short)f2bf(f0.z); av[3] = (short)f2bf(f0.w);
        av[4] = (short)f2bf(f1.x); av[5] = (short)f2bf(f1.y);
        av[6] = (short)f2bf(f1.z); av[7] = (short)f2bf(f1.w);
        a[ks] = av;
    }
    f32x4 acc[8];
    #pragma unroll
    for (int j = 0; j < 8; ++j) acc[j] = (f32x4){0.f, 0.f, 0.f, 0.f};
    #pragma unroll
    for (int j = 0; j < 8; ++j) {
        #pragma unroll
        for (int ks = 0; ks < 4; ++ks) {
            bf16x8 b = *(const bf16x8*)(wto + (size_t)(j * 16 + cl) * DM + ks * 32 + kc);
            acc[j] = __builtin_amdgcn_mfma_f32_16x16x32_bf16(a[ks], b, acc[j], 0, 0, 0);
        }
    }
    int r0w = rt + (lane >> 4) * 4;
    #pragma unroll
    for (int j = 0; j < 8; ++j)
        #pragma unroll
        for (int r = 0; r < 4; ++r)
            dout[(size_t)(r0w + r) * DM + j * 16 + cl] = acc[j][r];
}

extern "C" void kernel_launch(void* const* d_in, const int* in_sizes, int n_in,
                              void* d_out, int out_size, void* d_ws, size_t ws_size,
                              hipStream_t stream) {
    const float* x   = (const float*)d_in[0];
    const int*   ei  = (const int*)d_in[1];
    const float* ea  = (const float*)d_in[2];
    const float* Wq  = (const float*)d_in[3];
    const float* Wk  = (const float*)d_in[4];
    const float* Wv  = (const float*)d_in[5];
    const float* Wo  = (const float*)d_in[6];
    const float* Wek = (const float*)d_in[7];
    const float* Wev = (const float*)d_in[8];
    const float* Wg1 = (const float*)d_in[9];
    const float* Wg2 = (const float*)d_in[10];
    float* dout = (float*)d_out;

    float* ws = (float*)d_ws;
    float* q        = ws;                                   // NP*DM f32
    unsigned* kvp   = (unsigned*)(q + (size_t)NP * DM);     // NP*DM u32
    unsigned* qwekh = kvp + (size_t)NP * DM;                // NN*128 u32 (bf16 pairs)
    float* g2f      = (float*)(qwekh + (size_t)NN * 128);   // NE*8 f32
    int2* eb        = (int2*)(g2f + (size_t)NE * 8);        // NN*MAXDEG int2
    unsigned* eah   = (unsigned*)(eb + (size_t)NN * MAXDEG);// NE*16 u32 (bf16 pairs)
    int* cnt        = (int*)(eah + (size_t)NE * 16);        // NN
    unsigned short* wt = (unsigned short*)(cnt + NN);       // 3*DM*DM bf16
    unsigned short* wto = wt + 3 * DM * DM;                 // DM*DM bf16
    unsigned short* wg1t = wto + DM * DM;                   // DG*DE bf16
    unsigned short* wg2t = wg1t + DG * DE;                  // 16*DG bf16
    float* WekT     = (float*)(wg2t + 16 * DG);             // DE*DM f32

    k_prep<<<(NN + 255) / 256, 256, 0, stream>>>(Wq, Wk, Wv, wt, Wo, wto, Wek, WekT,
                                                 Wg1, wg1t, Wg2, wg2t, cnt);
    k_qkv<<<NP / 64, 256, 0, stream>>>(x, wt, q, kvp);
    k_qwek<<<512, 256, 0, stream>>>(q, WekT, qwekh);
    k_edge<<<NE / 64, 256, 0, stream>>>(ea, wg1t, wg2t, ei, cnt, eb, (float2*)g2f, eah);
    k_fused<<<NN / 8, 256, 0, stream>>>(q, (const unsigned long long*)kvp,
                                        qwekh, g2f, eah, eb, cnt, Wev, dout);
    k_final<<<(NN + 63) / 64, 256, 0, stream>>>(dout, wto);
}